// Round 12
// baseline (18.222 us; speedup 1.0000x reference)
//
#include <hip/hip_runtime.h>

typedef unsigned int uint;
typedef unsigned short ushort;

#define BATCH 2048
#define INF_  512
#define OUTF  256

#define PKMIN(d, a, b) asm("v_pk_min_f16 %0, %1, %2" : "=v"(d) : "v"(a), "v"(b))
#define PKMAXA(d, a)   asm("v_pk_max_f16 %0, %0, %1" : "+v"(d) : "v"(a))

#define LBAR  asm volatile("s_waitcnt lgkmcnt(0)\n\ts_barrier" ::: "memory")
#define XBAR  asm volatile("s_barrier" ::: "memory")

static __device__ __forceinline__ uint pkrtz(float a, float b) {
  typedef __fp16 half2_t __attribute__((ext_vector_type(2)));
  half2_t h = __builtin_amdgcn_cvt_pkrtz(a, b);
  return __builtin_bit_cast(uint, h);
}
static __device__ __forceinline__ float h2flo(uint u) {
  __fp16 h = __builtin_bit_cast(__fp16, (ushort)(u & 0xFFFF));
  return (float)h;
}
static __device__ __forceinline__ float h2fhi(uint u) {
  __fp16 h = __builtin_bit_cast(__fp16, (ushort)(u >> 16));
  return (float)h;
}

// ONE kernel, ONE node. Block = 512 threads (8 waves); out-tile 32x32.
// K=512 split 32 ways: slice s = w*4 + (lane>>4), 16 k each (granules 2s, 2s+1).
// Per-thread 8 rows x 8 cols x 16 k -> 1024 pk instr, 32 ds_read_b128.
// Whole K staged once; 3 barriers total (stage | compute | reduce | store).
// Grid 512 = 2 blocks/CU (64KB LDS) = 16 waves/CU = 4/SIMD.
//
// LDS (16B granules = 4 (k,k+1)-packed f16 pairs):
//  lsA[row(32)][slot(64)]: granule g at slot (g&56)|((g&7)^((row>>3)&1)).
//    read av[r]: 16 addrs/wave -> 8 quads x 2-way + 4-lane cg-broadcast: free.
//  lsB[kp(256)][cq(8)]: granule (kp,cq) at kp*8 + (cq^((kp>>3)&7)).
//    read bv: 16 addrs/wave -> 8 quads x 2-way + 4-lane rg-broadcast: free.
// Reduce: 32 slice-planes (32x32 f16 = 2KB) exactly fill lsA+lsB (64KB).
// XCD swizzle (T1): bid = c + 8x + 64m -> row-tile 8c+m, col-tile x; the 8
// col-blocks sharing an M-slab co-reside on XCD c.
__global__ __launch_bounds__(512, 4)
void crisp_one(const float* __restrict__ M, const float* __restrict__ W,
               float* __restrict__ out) {
  __shared__ uint4 lds[4096];          // 64 KB
  uint4* lsA = lds;                    // [32][64]
  uint4* lsB = lds + 2048;             // [256][8]

  const int t    = threadIdx.x;
  const int w    = t >> 6;
  const int lane = t & 63;
  const int s    = w * 4 + (lane >> 4);  // k-slice 0..31
  const int rg   = (lane >> 2) & 3;      // rows rg*8 + r
  const int cg   = lane & 3;             // cols cg*8 + c

  const int bid  = blockIdx.x;
  const int row0 = (((bid & 7) << 3) | (bid >> 6)) * 32;
  const int col0 = ((bid >> 3) & 7) * 32;

  // ---- stage: issue all global loads (compiler inserts fine-grained waits) ----
  float4 fa[8], fb[8];
#pragma unroll
  for (int j = 0; j < 4; j++) {        // A: row 8j+w, granule = lane
    const float* p = M + (size_t)(row0 + 8 * j + w) * INF_ + lane * 8;
    fa[2 * j]     = *(const float4*)p;
    fa[2 * j + 1] = *(const float4*)(p + 4);
  }
#pragma unroll
  for (int j = 0; j < 4; j++) {        // B: kp = 64j+8w+(lane>>3), cq = lane&7
    int kp = j * 64 + 8 * w + (lane >> 3);
    const float* q = W + (size_t)(2 * kp) * OUTF + col0 + (lane & 7) * 4;
    fb[2 * j]     = *(const float4*)q;           // k even
    fb[2 * j + 1] = *(const float4*)(q + OUTF);  // k odd
  }
  // ---- pack f32 -> (k,k+1) f16 pairs, swizzled LDS writes ----
#pragma unroll
  for (int j = 0; j < 4; j++) {
    int row  = 8 * j + w;
    int slot = (lane & 56) | ((lane & 7) ^ (j & 1));  // (row>>3)&1 == j&1
    lsA[row * 64 + slot] = make_uint4(
        pkrtz(fa[2 * j].x, fa[2 * j].y), pkrtz(fa[2 * j].z, fa[2 * j].w),
        pkrtz(fa[2 * j + 1].x, fa[2 * j + 1].y),
        pkrtz(fa[2 * j + 1].z, fa[2 * j + 1].w));
  }
#pragma unroll
  for (int j = 0; j < 4; j++) {
    int kp  = j * 64 + 8 * w + (lane >> 3);
    int cqp = (lane & 7) ^ ((kp >> 3) & 7);           // (kp>>3)&7 == w
    lsB[kp * 8 + cqp] = make_uint4(
        pkrtz(fb[2 * j].x, fb[2 * j + 1].x), pkrtz(fb[2 * j].y, fb[2 * j + 1].y),
        pkrtz(fb[2 * j].z, fb[2 * j + 1].z), pkrtz(fb[2 * j].w, fb[2 * j + 1].w));
  }
  LBAR;

  // ---- compute: slice s, 8r x 8c x 16k ----
  uint acc[8][8];
#pragma unroll
  for (int r = 0; r < 8; r++)
#pragma unroll
    for (int c = 0; c < 8; c++) acc[r][c] = 0xFC00FC00u;

#pragma unroll
  for (int gq = 0; gq < 2; gq++) {
    const int g = s * 2 + gq;
    uint4 av[8];
#pragma unroll
    for (int r = 0; r < 8; r++) {
      int row = rg * 8 + r;
      av[r] = lsA[row * 64 + ((g & 56) | ((g & 7) ^ (rg & 1)))];
    }
#pragma unroll
    for (int kpl = 0; kpl < 4; kpl++) {
      const int kp = g * 4 + kpl;
      const int sx = (kp >> 3) & 7;    // == s&7
      uint4 bv0 = lsB[kp * 8 + ((cg * 2) ^ sx)];
      uint4 bv1 = lsB[kp * 8 + ((cg * 2 + 1) ^ sx)];
#pragma unroll
      for (int r = 0; r < 8; r++) {
        uint a = (kpl == 0) ? av[r].x : (kpl == 1) ? av[r].y
                 : (kpl == 2) ? av[r].z : av[r].w;
        uint t0, t1, t2, t3, t4, t5, t6, t7;
        PKMIN(t0, a, bv0.x); PKMIN(t1, a, bv0.y);
        PKMIN(t2, a, bv0.z); PKMIN(t3, a, bv0.w);
        PKMIN(t4, a, bv1.x); PKMIN(t5, a, bv1.y);
        PKMIN(t6, a, bv1.z); PKMIN(t7, a, bv1.w);
        PKMAXA(acc[r][0], t0); PKMAXA(acc[r][1], t1);
        PKMAXA(acc[r][2], t2); PKMAXA(acc[r][3], t3);
        PKMAXA(acc[r][4], t4); PKMAXA(acc[r][5], t5);
        PKMAXA(acc[r][6], t6); PKMAXA(acc[r][7], t7);
      }
    }
  }
  XBAR;  // all waves done reading lsA/lsB (reads consumed before barrier)

  // ---- reduce: 32 slice-planes (2KB each) reuse the whole 64KB LDS ----
  uint* pl = (uint*)lds;
#pragma unroll
  for (int r = 0; r < 8; r++) {
    uint m[8];
#pragma unroll
    for (int c = 0; c < 8; c++) {
      uint hi = acc[r][c] >> 16;
      PKMAXA(acc[r][c], hi);           // low16 = max over the k-pair
      m[c] = acc[r][c] & 0xFFFFu;
    }
    ((uint4*)pl)[s * 128 + (rg * 8 + r) * 4 + cg] = make_uint4(
        m[0] | (m[1] << 16), m[2] | (m[3] << 16),
        m[4] | (m[5] << 16), m[6] | (m[7] << 16));
  }
  LBAR;

  // ---- fold 32 planes, 2 f32 outputs per thread ----
  {
    uint v = pl[t];
#pragma unroll
    for (int p = 1; p < 32; p++) {
      uint u = pl[p * 512 + t];
      PKMAXA(v, u);
    }
    int row = t >> 4, cp = t & 15;
    *(float2*)&out[(size_t)(row0 + row) * OUTF + col0 + 2 * cp] =
        make_float2(h2flo(v), h2fhi(v));
  }
}

extern "C" void kernel_launch(void* const* d_in, const int* in_sizes, int n_in,
                              void* d_out, int out_size, void* d_ws, size_t ws_size,
                              hipStream_t stream) {
  const float* M = (const float*)d_in[0];
  const float* W = (const float*)d_in[1];
  float* out = (float*)d_out;
  crisp_one<<<512, 512, 0, stream>>>(M, W, out);
}

// Round 13
// 17.441 us; speedup vs baseline: 1.0448x; 1.0448x over previous
//
#include <hip/hip_runtime.h>

typedef unsigned int uint;
typedef unsigned short ushort;

#define BATCH 2048
#define INF_  512
#define OUTF  256

#define PKMIN(d, a, b) asm("v_pk_min_f16 %0, %1, %2" : "=v"(d) : "v"(a), "v"(b))
#define PKMAXA(d, a)   asm("v_pk_max_f16 %0, %0, %1" : "+v"(d) : "v"(a))

#define VW0   asm volatile("s_waitcnt vmcnt(0)" ::: "memory")
#define LBAR  asm volatile("s_waitcnt lgkmcnt(0)\n\ts_barrier" ::: "memory")
#define XBAR  asm volatile("s_barrier" ::: "memory")

static __device__ __forceinline__ uint pkrtz(float a, float b) {
  typedef __fp16 half2_t __attribute__((ext_vector_type(2)));
  half2_t h = __builtin_amdgcn_cvt_pkrtz(a, b);
  return __builtin_bit_cast(uint, h);
}
static __device__ __forceinline__ float h2flo(uint u) {
  __fp16 h = __builtin_bit_cast(__fp16, (ushort)(u & 0xFFFF));
  return (float)h;
}
static __device__ __forceinline__ float h2fhi(uint u) {
  __fp16 h = __builtin_bit_cast(__fp16, (ushort)(u >> 16));
  return (float)h;
}

// CHAMPION (R11, 17.44us) restored verbatim.
// ONE kernel, ONE node. Block = 512 threads (8 waves); out-tile 32x32.
// K=512 split 16 ways in-block: slice s = wave*2 + halfwave, 32 k each.
// Per-thread 4 rows x 8 cols, 32 k -> 1024 pk instr, 48 ds_read_b128.
// Whole K staged once; 3 barriers total. Grid 512 = 2 blocks/CU (64KB LDS)
// = 16 waves/CU = 4/SIMD.
// Compute-phase balance (measured-constant arithmetic): LDS 9216 cyc/CU vs
// VALU 8192 cyc/CU -> balanced; reshaping the tile only shifts the binding
// pipe (R12 lesson). Reduce: 16 slice-planes, 4-wave fold.
__global__ __launch_bounds__(512, 4)
void crisp_one(const float* __restrict__ M, const float* __restrict__ W,
               float* __restrict__ out) {
  __shared__ uint4 lsA[2048];  // 32 KB [32 rows][64 slots]
  __shared__ uint4 lsB[2048];  // 32 KB [256 kp][8 cq]

  const int t    = threadIdx.x;
  const int w    = t >> 6;
  const int lane = t & 63;
  const int ks   = lane >> 5;
  const int rg   = (lane >> 2) & 7;  // rows rg*4 + r
  const int cg   = lane & 3;         // cols cg*8 .. +7
  const int s    = w * 2 + ks;       // k-slice 0..15

  const int bid  = blockIdx.x;
  const int row0 = (((bid & 7) << 3) | (bid >> 6)) * 32;  // XCD swizzle (T1)
  const int col0 = ((bid >> 3) & 7) * 32;

  // ---- stage: issue ALL global loads, then one drain ----
  float4 fa[8], fb[8];
#pragma unroll
  for (int j = 0; j < 4; j++) {
    int idx = j * 512 + t;           // A granule 0..2047
    int row = idx >> 6, g = idx & 63;
    const float* p = M + (size_t)(row0 + row) * INF_ + g * 8;
    fa[2 * j]     = *(const float4*)p;
    fa[2 * j + 1] = *(const float4*)(p + 4);
  }
#pragma unroll
  for (int j = 0; j < 4; j++) {
    int idx = j * 512 + t;           // B granule 0..2047
    int kp = idx >> 3, cq = idx & 7;
    const float* q = W + (size_t)(2 * kp) * OUTF + col0 + cq * 4;
    fb[2 * j]     = *(const float4*)q;
    fb[2 * j + 1] = *(const float4*)(q + OUTF);
  }
  VW0;
  // ---- pack f32 -> packed-pair f16, write LDS ----
#pragma unroll
  for (int j = 0; j < 4; j++) {
    int idx = j * 512 + t;
    int row = idx >> 6, g = idx & 63;
    int slot = (g & 56) | ((g ^ (row >> 2)) & 7);
    lsA[row * 64 + slot] = make_uint4(
        pkrtz(fa[2 * j].x, fa[2 * j].y), pkrtz(fa[2 * j].z, fa[2 * j].w),
        pkrtz(fa[2 * j + 1].x, fa[2 * j + 1].y),
        pkrtz(fa[2 * j + 1].z, fa[2 * j + 1].w));
    lsB[idx] = make_uint4(                       // (k_even,k_odd) per col
        pkrtz(fb[2 * j].x, fb[2 * j + 1].x), pkrtz(fb[2 * j].y, fb[2 * j + 1].y),
        pkrtz(fb[2 * j].z, fb[2 * j + 1].z), pkrtz(fb[2 * j].w, fb[2 * j + 1].w));
  }
  LBAR;

  // ---- compute: slice s (granules 4s..4s+3), 4r x 8c ----
  uint acc[4][8];
#pragma unroll
  for (int r = 0; r < 4; r++)
#pragma unroll
    for (int c = 0; c < 8; c++) acc[r][c] = 0xFC00FC00u;

#pragma unroll
  for (int gq = 0; gq < 4; gq++) {
    const int g = s * 4 + gq;
    uint4 av[4];
#pragma unroll
    for (int r = 0; r < 4; r++)
      av[r] = lsA[(rg * 4 + r) * 64 + ((g & 56) | ((g ^ rg) & 7))];
#pragma unroll
    for (int kpl = 0; kpl < 4; kpl++) {
      const int kp = g * 4 + kpl;
      uint4 bv0 = lsB[kp * 8 + cg * 2];
      uint4 bv1 = lsB[kp * 8 + cg * 2 + 1];
#pragma unroll
      for (int r = 0; r < 4; r++) {
        uint a = (kpl == 0) ? av[r].x : (kpl == 1) ? av[r].y
                 : (kpl == 2) ? av[r].z : av[r].w;
        uint t0, t1, t2, t3, t4, t5, t6, t7;
        PKMIN(t0, a, bv0.x); PKMIN(t1, a, bv0.y);
        PKMIN(t2, a, bv0.z); PKMIN(t3, a, bv0.w);
        PKMIN(t4, a, bv1.x); PKMIN(t5, a, bv1.y);
        PKMIN(t6, a, bv1.z); PKMIN(t7, a, bv1.w);
        PKMAXA(acc[r][0], t0); PKMAXA(acc[r][1], t1);
        PKMAXA(acc[r][2], t2); PKMAXA(acc[r][3], t3);
        PKMAXA(acc[r][4], t4); PKMAXA(acc[r][5], t5);
        PKMAXA(acc[r][6], t6); PKMAXA(acc[r][7], t7);
      }
    }
  }
  XBAR;  // all waves done reading lsA/lsB (reads consumed before barrier)

  // ---- reduce: 16 slice-planes (32x32 f16 = 2KB) in lsA region ----
  uint* pl = (uint*)lsA + s * 512;
#pragma unroll
  for (int r = 0; r < 4; r++) {
    uint m[8];
#pragma unroll
    for (int c = 0; c < 8; c++) {
      uint hi = acc[r][c] >> 16;
      PKMAXA(acc[r][c], hi);           // low16 = max(k_even, k_odd)
      m[c] = acc[r][c] & 0xFFFFu;
    }
    ((uint4*)pl)[(rg * 4 + r) * 4 + cg] = make_uint4(
        m[0] | (m[1] << 16), m[2] | (m[3] << 16),
        m[4] | (m[5] << 16), m[6] | (m[7] << 16));
  }
  LBAR;

  if (t < 256) {  // fold 16 planes, 4 outputs/thread, f32 store
    uint2 v = ((const uint2*)lsA)[t];
#pragma unroll
    for (int p = 1; p < 16; p++) {
      uint2 u = ((const uint2*)lsA)[p * 256 + t];
      PKMAXA(v.x, u.x);
      PKMAXA(v.y, u.y);
    }
    int row = t >> 3, col = (t & 7) * 4;
    *(float4*)&out[(size_t)(row0 + row) * OUTF + col0 + col] =
        make_float4(h2flo(v.x), h2fhi(v.x), h2flo(v.y), h2fhi(v.y));
  }
}

extern "C" void kernel_launch(void* const* d_in, const int* in_sizes, int n_in,
                              void* d_out, int out_size, void* d_ws, size_t ws_size,
                              hipStream_t stream) {
  const float* M = (const float*)d_in[0];
  const float* W = (const float*)d_in[1];
  float* out = (float*)d_out;
  crisp_one<<<512, 512, 0, stream>>>(M, W, out);
}

// Round 14
// 17.434 us; speedup vs baseline: 1.0452x; 1.0004x over previous
//
#include <hip/hip_runtime.h>

typedef unsigned int uint;
typedef unsigned short ushort;

#define BATCH 2048
#define INF_  512
#define OUTF  256

#define PKMIN(d, a, b) asm("v_pk_min_f16 %0, %1, %2" : "=v"(d) : "v"(a), "v"(b))
#define PKMAXA(d, a)   asm("v_pk_max_f16 %0, %0, %1" : "+v"(d) : "v"(a))

#define VW0   asm volatile("s_waitcnt vmcnt(0)" ::: "memory")
#define LBAR  asm volatile("s_waitcnt lgkmcnt(0)\n\ts_barrier" ::: "memory")
#define XBAR  asm volatile("s_barrier" ::: "memory")

static __device__ __forceinline__ uint pkrtz(float a, float b) {
  typedef __fp16 half2_t __attribute__((ext_vector_type(2)));
  half2_t h = __builtin_amdgcn_cvt_pkrtz(a, b);
  return __builtin_bit_cast(uint, h);
}
static __device__ __forceinline__ float h2flo(uint u) {
  __fp16 h = __builtin_bit_cast(__fp16, (ushort)(u & 0xFFFF));
  return (float)h;
}
static __device__ __forceinline__ float h2fhi(uint u) {
  __fp16 h = __builtin_bit_cast(__fp16, (ushort)(u >> 16));
  return (float)h;
}

// CHAMPION (R11, 17.44us) restored verbatim.
// ONE kernel, ONE node. Block = 512 threads (8 waves); out-tile 32x32.
// K=512 split 16 ways in-block: slice s = wave*2 + halfwave, 32 k each.
// Per-thread 4 rows x 8 cols, 32 k -> 1024 pk instr, 48 ds_read_b128.
// Whole K staged once; 3 barriers total. Grid 512 = 2 blocks/CU (64KB LDS)
// = 16 waves/CU = 4/SIMD.
// Compute-phase balance (measured-constant arithmetic): LDS 9216 cyc/CU vs
// VALU 8192 cyc/CU -> balanced; reshaping the tile only shifts the binding
// pipe (R12 lesson). Reduce: 16 slice-planes, 4-wave fold.
__global__ __launch_bounds__(512, 4)
void crisp_one(const float* __restrict__ M, const float* __restrict__ W,
               float* __restrict__ out) {
  __shared__ uint4 lsA[2048];  // 32 KB [32 rows][64 slots]
  __shared__ uint4 lsB[2048];  // 32 KB [256 kp][8 cq]

  const int t    = threadIdx.x;
  const int w    = t >> 6;
  const int lane = t & 63;
  const int ks   = lane >> 5;
  const int rg   = (lane >> 2) & 7;  // rows rg*4 + r
  const int cg   = lane & 3;         // cols cg*8 .. +7
  const int s    = w * 2 + ks;       // k-slice 0..15

  const int bid  = blockIdx.x;
  const int row0 = (((bid & 7) << 3) | (bid >> 6)) * 32;  // XCD swizzle (T1)
  const int col0 = ((bid >> 3) & 7) * 32;

  // ---- stage: issue ALL global loads, then one drain ----
  float4 fa[8], fb[8];
#pragma unroll
  for (int j = 0; j < 4; j++) {
    int idx = j * 512 + t;           // A granule 0..2047
    int row = idx >> 6, g = idx & 63;
    const float* p = M + (size_t)(row0 + row) * INF_ + g * 8;
    fa[2 * j]     = *(const float4*)p;
    fa[2 * j + 1] = *(const float4*)(p + 4);
  }
#pragma unroll
  for (int j = 0; j < 4; j++) {
    int idx = j * 512 + t;           // B granule 0..2047
    int kp = idx >> 3, cq = idx & 7;
    const float* q = W + (size_t)(2 * kp) * OUTF + col0 + cq * 4;
    fb[2 * j]     = *(const float4*)q;
    fb[2 * j + 1] = *(const float4*)(q + OUTF);
  }
  VW0;
  // ---- pack f32 -> packed-pair f16, write LDS ----
#pragma unroll
  for (int j = 0; j < 4; j++) {
    int idx = j * 512 + t;
    int row = idx >> 6, g = idx & 63;
    int slot = (g & 56) | ((g ^ (row >> 2)) & 7);
    lsA[row * 64 + slot] = make_uint4(
        pkrtz(fa[2 * j].x, fa[2 * j].y), pkrtz(fa[2 * j].z, fa[2 * j].w),
        pkrtz(fa[2 * j + 1].x, fa[2 * j + 1].y),
        pkrtz(fa[2 * j + 1].z, fa[2 * j + 1].w));
    lsB[idx] = make_uint4(                       // (k_even,k_odd) per col
        pkrtz(fb[2 * j].x, fb[2 * j + 1].x), pkrtz(fb[2 * j].y, fb[2 * j + 1].y),
        pkrtz(fb[2 * j].z, fb[2 * j + 1].z), pkrtz(fb[2 * j].w, fb[2 * j + 1].w));
  }
  LBAR;

  // ---- compute: slice s (granules 4s..4s+3), 4r x 8c ----
  uint acc[4][8];
#pragma unroll
  for (int r = 0; r < 4; r++)
#pragma unroll
    for (int c = 0; c < 8; c++) acc[r][c] = 0xFC00FC00u;

#pragma unroll
  for (int gq = 0; gq < 4; gq++) {
    const int g = s * 4 + gq;
    uint4 av[4];
#pragma unroll
    for (int r = 0; r < 4; r++)
      av[r] = lsA[(rg * 4 + r) * 64 + ((g & 56) | ((g ^ rg) & 7))];
#pragma unroll
    for (int kpl = 0; kpl < 4; kpl++) {
      const int kp = g * 4 + kpl;
      uint4 bv0 = lsB[kp * 8 + cg * 2];
      uint4 bv1 = lsB[kp * 8 + cg * 2 + 1];
#pragma unroll
      for (int r = 0; r < 4; r++) {
        uint a = (kpl == 0) ? av[r].x : (kpl == 1) ? av[r].y
                 : (kpl == 2) ? av[r].z : av[r].w;
        uint t0, t1, t2, t3, t4, t5, t6, t7;
        PKMIN(t0, a, bv0.x); PKMIN(t1, a, bv0.y);
        PKMIN(t2, a, bv0.z); PKMIN(t3, a, bv0.w);
        PKMIN(t4, a, bv1.x); PKMIN(t5, a, bv1.y);
        PKMIN(t6, a, bv1.z); PKMIN(t7, a, bv1.w);
        PKMAXA(acc[r][0], t0); PKMAXA(acc[r][1], t1);
        PKMAXA(acc[r][2], t2); PKMAXA(acc[r][3], t3);
        PKMAXA(acc[r][4], t4); PKMAXA(acc[r][5], t5);
        PKMAXA(acc[r][6], t6); PKMAXA(acc[r][7], t7);
      }
    }
  }
  XBAR;  // all waves done reading lsA/lsB (reads consumed before barrier)

  // ---- reduce: 16 slice-planes (32x32 f16 = 2KB) in lsA region ----
  uint* pl = (uint*)lsA + s * 512;
#pragma unroll
  for (int r = 0; r < 4; r++) {
    uint m[8];
#pragma unroll
    for (int c = 0; c < 8; c++) {
      uint hi = acc[r][c] >> 16;
      PKMAXA(acc[r][c], hi);           // low16 = max(k_even, k_odd)
      m[c] = acc[r][c] & 0xFFFFu;
    }
    ((uint4*)pl)[(rg * 4 + r) * 4 + cg] = make_uint4(
        m[0] | (m[1] << 16), m[2] | (m[3] << 16),
        m[4] | (m[5] << 16), m[6] | (m[7] << 16));
  }
  LBAR;

  if (t < 256) {  // fold 16 planes, 4 outputs/thread, f32 store
    uint2 v = ((const uint2*)lsA)[t];
#pragma unroll
    for (int p = 1; p < 16; p++) {
      uint2 u = ((const uint2*)lsA)[p * 256 + t];
      PKMAXA(v.x, u.x);
      PKMAXA(v.y, u.y);
    }
    int row = t >> 3, col = (t & 7) * 4;
    *(float4*)&out[(size_t)(row0 + row) * OUTF + col0 + col] =
        make_float4(h2flo(v.x), h2fhi(v.x), h2flo(v.y), h2fhi(v.y));
  }
}

extern "C" void kernel_launch(void* const* d_in, const int* in_sizes, int n_in,
                              void* d_out, int out_size, void* d_ws, size_t ws_size,
                              hipStream_t stream) {
  const float* M = (const float*)d_in[0];
  const float* W = (const float*)d_in[1];
  float* out = (float*)d_out;
  crisp_one<<<512, 512, 0, stream>>>(M, W, out);
}